// Round 12
// baseline (498.856 us; speedup 1.0000x reference)
//
#include <hip/hip_runtime.h>
#include <hip/hip_fp16.h>

// MsgPassingNN: 3 rounds of edge-MLP + segment_sum + node-MLP.
// N=100000 nodes (D=16), E=3200000 edges.
// fe: 32 -> 9 (relu) -> 9 (relu) -> 9 ; fx: 25 -> 9 (relu) -> 9 (relu) -> 16
//
// R14 = R10 exactly (best verified: 492us; R13's m-stride/grid deltas
// reverted) + fp16 storage of base_s (the random-gather array):
//   * bases -> 9 halves padded to 32B rows: footprint 6.4 -> 3.2 MB, now
//     FITS the 4 MB per-XCD L2 (R10's FETCH=94MB showed ~45% of random
//     gathers missed to HBM at ~900cy). 32|64 -> a row never crosses a
//     cache line (still ONE line per gather — R11's split-array mistake
//     doubled lines and regressed despite residency). VMEM ops per gather
//     3 -> 2 (uint4 + uint). ~10 cvt_f32_f16/edge on a 23%-busy VALU.
//   * everything else byte-identical to R10: 1 thread/edge, u32 sed
//     (d_local:7|src:17), two-level sort (bsort bucket=dst>>7 + lsort
//     in-bucket counting sort), weights via wave-uniform s_load (zero LDS
//     in edge/node), fe layer-1 hoisted per node (base1 f32 stride 12 —
//     dst side is L1-friendly, keep full precision), fe layer-3 hoisted
//     to node (m = W3^T sum relu(h2) + deg*b3, deg free from ballot),
//     branchless edge + wave-segmented scan, m stride 10, node writes out
//     in place.

constexpr int NN = 100000;
constexpr int NE = 3200000;
constexpr int NBK = (NN + 127) / 128;      // 782 buckets of 128 nodes
constexpr int SLOT = 8192;                 // sed slots per bucket (avg fill 4096)
constexpr int EPB = 4096;                  // edges per bsort block (16/thread)
constexpr int NBLK_SORT = (NE + EPB - 1) / EPB;   // 782
constexpr int NB_NODE = (NN + 255) / 256;  // 391

__device__ __forceinline__ unsigned packh2(float a, float b)
{
    __half2 h = __floats2half2_rn(a, b);
    return *reinterpret_cast<unsigned*>(&h);
}

// ---------------- pass 1: bucket sort (dst>>7) ----------------
// gcursor[bin] = running count (memset to 0 before launch)

__global__ __launch_bounds__(256) void bsort_k(const int* __restrict__ src,
                                               const int* __restrict__ dst,
                                               int* __restrict__ gcursor,
                                               unsigned* __restrict__ sed)
{
    __shared__ int lhist[NBK];
    __shared__ int lbase[NBK];
    const int t = threadIdx.x;
    for (int i = t; i < NBK; i += 256) lhist[i] = 0;
    __syncthreads();

    const int blkbase = blockIdx.x * EPB;
    unsigned pr[16], sv[16];
    #pragma unroll
    for (int k = 0; k < 16; ++k) {
        const int e = blkbase + k * 256 + t;
        if (e < NE) {
            const int d = dst[e];
            const int s = src[e];
            const int bin = d >> 7;
            const int r = atomicAdd(&lhist[bin], 1);      // LDS atomic
            pr[k] = ((unsigned)bin << 13) | (unsigned)r;  // r < 4096 < 2^13
            sv[k] = ((unsigned)(d & 127) << 17) | (unsigned)s;
        } else {
            pr[k] = 0xFFFFFFFFu;
        }
    }
    __syncthreads();

    for (int i = t; i < NBK; i += 256) {
        const int c = lhist[i];
        if (c) lbase[i] = atomicAdd(&gcursor[i], c);      // offset within bucket
    }
    __syncthreads();

    #pragma unroll
    for (int k = 0; k < 16; ++k) {
        if (pr[k] != 0xFFFFFFFFu) {
            const int bin = (int)(pr[k] >> 13);
            const int r = (int)(pr[k] & 0x1FFFu);
            sed[(size_t)bin * SLOT + lbase[bin] + r] = sv[k];
        }
    }
}

// ---------------- pass 2: in-bucket counting sort by d_local (in place) ----------------

__global__ __launch_bounds__(512) void lsort_k(unsigned* __restrict__ sed,
                                               const int* __restrict__ gcursor)
{
    __shared__ unsigned buf[SLOT];    // 32 KB
    __shared__ unsigned obuf[SLOT];   // 32 KB
    __shared__ int hist[128];
    __shared__ int cur[128];
    const int t = threadIdx.x;
    const int b = blockIdx.x;
    const int base = b * SLOT;
    int fill = gcursor[b];
    if (fill > SLOT) fill = SLOT;     // safety clamp (never hit for this input)

    if (t < 128) hist[t] = 0;
    __syncthreads();
    for (int i = t; i < fill; i += 512) {
        unsigned v = sed[base + i];
        buf[i] = v;
        atomicAdd(&hist[v >> 17], 1);
    }
    __syncthreads();
    // exclusive scan of 128 bins (Hillis-Steele in LDS)
    if (t < 128) cur[t] = hist[t];
    __syncthreads();
    for (int off = 1; off < 128; off <<= 1) {
        int a = (t < 128 && t >= off) ? cur[t - off] : 0;
        __syncthreads();
        if (t < 128) cur[t] += a;
        __syncthreads();
    }
    if (t < 128) cur[t] -= hist[t];   // exclusive prefix
    __syncthreads();
    for (int i = t; i < fill; i += 512) {
        unsigned v = buf[i];
        int r = atomicAdd(&cur[v >> 17], 1);
        obuf[r] = v;
    }
    __syncthreads();
    for (int i = t; i < fill; i += 512) sed[base + i] = obuf[i];
}

// ---------------- round-0 prologue: base1 + base_s(fp16) from X0, zero m ----------------

__global__ __launch_bounds__(256) void base_k(const float* __restrict__ X,
                                              const float* __restrict__ feW1,
                                              const float* __restrict__ feb1,
                                              float* __restrict__ base1,
                                              __half* __restrict__ basesh,
                                              float* __restrict__ m)
{
    const int n = blockIdx.x * 256 + threadIdx.x;
    if (n >= NN) return;

    float x[16];
    const float4* p = reinterpret_cast<const float4*>(X + (size_t)n * 16);
    #pragma unroll
    for (int q = 0; q < 4; ++q) {
        float4 v = p[q];
        x[4*q] = v.x; x[4*q+1] = v.y; x[4*q+2] = v.z; x[4*q+3] = v.w;
    }
    float bd[9];
    #pragma unroll
    for (int j = 0; j < 9; ++j) bd[j] = feb1[j];
    #pragma unroll
    for (int i = 0; i < 16; ++i) {
        const float xi = x[i];
        #pragma unroll
        for (int j = 0; j < 9; ++j) bd[j] = fmaf(xi, feW1[i * 9 + j], bd[j]);
    }
    float bs[9];
    #pragma unroll
    for (int j = 0; j < 9; ++j) bs[j] = 0.f;
    #pragma unroll
    for (int i = 0; i < 16; ++i) {
        const float xi = x[i];
        #pragma unroll
        for (int j = 0; j < 9; ++j) bs[j] = fmaf(xi, feW1[(16 + i) * 9 + j], bs[j]);
    }
    float* bp = base1 + (size_t)n * 12;
    #pragma unroll
    for (int j = 0; j < 9; ++j) bp[j] = bd[j];

    // bases row: 9 halves in a 32B row (16 halves stride)
    uint4 pv;
    pv.x = packh2(bs[0], bs[1]);
    pv.y = packh2(bs[2], bs[3]);
    pv.z = packh2(bs[4], bs[5]);
    pv.w = packh2(bs[6], bs[7]);
    *reinterpret_cast<uint4*>(basesh + (size_t)n * 16) = pv;
    *reinterpret_cast<unsigned*>(basesh + (size_t)n * 16 + 8) = packh2(bs[8], 0.f);

    float* mp = m + (size_t)n * 10;
    #pragma unroll
    for (int j = 0; j < 10; ++j) mp[j] = 0.f;
}

// ---------------- edge round: 1 thread / sorted slot, wave scan of h2 ----------------
// No LDS, no barrier: weights read via uniform addresses (s_load).
// Random gather: ONE 32B fp16 row per edge; 3.2MB hot set -> per-XCD L2 resident.

__global__ __launch_bounds__(256) void edge13_k(
    const float* __restrict__ base1,
    const __half* __restrict__ basesh,
    const unsigned* __restrict__ sed,
    const int* __restrict__ gcursor,
    const float* __restrict__ feW2, const float* __restrict__ feb2,
    float* __restrict__ m)    // NN x 10: 9 h2-sums + deg
{
    const int t = threadIdx.x;
    const int b = blockIdx.x >> 5;                 // bucket (SLOT/256 = 32 blocks/bucket)
    const int idx0 = (blockIdx.x & 31) * 256;      // slot offset within bucket
    const int fill = gcursor[b];
    if (idx0 >= fill) return;                      // uniform early exit

    const int idx = idx0 + t;
    const bool valid = idx < fill;
    const int lane = t & 63;
    const int cidx = valid ? idx : fill - 1;       // clamp to a real edge
    const unsigned pk = sed[(size_t)b * SLOT + cidx];
    const int dla = (int)(pk >> 17);               // address-safe d_local
    const int s   = (int)(pk & 0x1FFFFu);
    const int dl  = valid ? dla : 128 + lane;      // sentinel: own segment

    // h1 = relu(base1[d] + base_s[s]); consecutive lanes share d -> L1 hits
    float a[9];
    {
        const float4* pb = reinterpret_cast<const float4*>(base1 + (size_t)(b * 128 + dla) * 12);
        float4 b0 = pb[0], b1 = pb[1];
        const float b8 = base1[(size_t)(b * 128 + dla) * 12 + 8];

        union { uint4 u; __half2 h[4]; } uu;
        uu.u = *reinterpret_cast<const uint4*>(basesh + (size_t)s * 16);
        const unsigned u8 = *reinterpret_cast<const unsigned*>(basesh + (size_t)s * 16 + 8);
        const float2 f01 = __half22float2(uu.h[0]);
        const float2 f23 = __half22float2(uu.h[1]);
        const float2 f45 = __half22float2(uu.h[2]);
        const float2 f67 = __half22float2(uu.h[3]);
        __half2 h8x = *reinterpret_cast<const __half2*>(&u8);
        const float c8 = __low2float(h8x);

        a[0] = b0.x + f01.x; a[1] = b0.y + f01.y; a[2] = b0.z + f23.x; a[3] = b0.w + f23.y;
        a[4] = b1.x + f45.x; a[5] = b1.y + f45.y; a[6] = b1.z + f67.x; a[7] = b1.w + f67.y;
        a[8] = b8 + c8;
    }
    #pragma unroll
    for (int j = 0; j < 9; ++j) a[j] = fmaxf(a[j], 0.f);

    // h2 = relu(W2^T a + b2); weights via scalar loads (uniform addresses)
    float o[9];
    #pragma unroll
    for (int j = 0; j < 9; ++j) o[j] = feb2[j];
    #pragma unroll
    for (int i = 0; i < 9; ++i) {
        const float ai = a[i];
        #pragma unroll
        for (int j = 0; j < 9; ++j) o[j] = fmaf(ai, feW2[i * 9 + j], o[j]);
    }
    #pragma unroll
    for (int j = 0; j < 9; ++j) o[j] = fmaxf(o[j], 0.f);

    // segmented inclusive scan by dl over the 64-lane wave (dl sorted;
    // invalid lanes are isolated singleton segments -> garbage stays put)
    const int dprev = __shfl_up(dl, 1);
    const bool head = (lane == 0) || (dprev != dl);
    const unsigned long long hm = __ballot(head);
    const int dist = __clzll((long long)(hm << (63 - lane)));  // 0 if head
    #pragma unroll
    for (int off = 1; off < 64; off <<= 1) {
        const bool ok = (dist >= off);
        #pragma unroll
        for (int j = 0; j < 9; ++j) {
            const float ov = __shfl_up(o[j], off);
            o[j] += ok ? ov : 0.f;
        }
    }
    const bool tail = (lane == 63) || (((hm >> (lane + 1)) & 1ull) != 0ull);
    if (tail && valid) {                            // segment tail -> global m
        float* mp = m + (size_t)(b * 128 + dl) * 10;
        #pragma unroll
        for (int j = 0; j < 9; ++j) atomicAdd(mp + j, o[j]);
        atomicAdd(mp + 9, (float)(dist + 1));       // segment length = free count
    }
}

// ---------------- node round: W3/b3 + fx MLP + zero m + next bases ----------------
// No LDS: all weights wave-uniform -> scalar loads from constant cache.

__global__ __launch_bounds__(256) void node11_k(
    const float* __restrict__ Xin, float* __restrict__ m,
    const float* __restrict__ fxW1, const float* __restrict__ fxb1,
    const float* __restrict__ fxW2, const float* __restrict__ fxb2,
    const float* __restrict__ fxW3, const float* __restrict__ fxb3,
    const float* __restrict__ feW1, const float* __restrict__ feb1,
    const float* __restrict__ feW3, const float* __restrict__ feb3,
    float* __restrict__ Xout, float* __restrict__ base1out,
    __half* __restrict__ basesh)
{
    const int n = blockIdx.x * 256 + threadIdx.x;
    if (n >= NN) return;

    float xr[16];
    {
        const float4* p = reinterpret_cast<const float4*>(Xin + (size_t)n * 16);
        #pragma unroll
        for (int q = 0; q < 4; ++q) {
            float4 v = p[q];
            xr[4*q] = v.x; xr[4*q+1] = v.y; xr[4*q+2] = v.z; xr[4*q+3] = v.w;
        }
    }
    float S[9], deg;
    float* mp = m + (size_t)n * 10;
    #pragma unroll
    for (int j = 0; j < 9; ++j) S[j] = mp[j];
    deg = mp[9];
    #pragma unroll
    for (int j = 0; j < 10; ++j) mp[j] = 0.f;    // ready for next round

    // m = W3^T S + deg * b3   (fe layer-3, hoisted from the edge loop)
    float mm[9];
    #pragma unroll
    for (int j = 0; j < 9; ++j) mm[j] = deg * feb3[j];
    #pragma unroll
    for (int i = 0; i < 9; ++i) {
        const float si = S[i];
        #pragma unroll
        for (int j = 0; j < 9; ++j) mm[j] = fmaf(si, feW3[i * 9 + j], mm[j]);
    }

    float h1[9];
    #pragma unroll
    for (int j = 0; j < 9; ++j) h1[j] = fxb1[j];
    #pragma unroll
    for (int i = 0; i < 16; ++i) {
        const float xi = xr[i];
        #pragma unroll
        for (int j = 0; j < 9; ++j) h1[j] = fmaf(xi, fxW1[i * 9 + j], h1[j]);
    }
    #pragma unroll
    for (int i = 0; i < 9; ++i) {
        const float xi = mm[i];
        #pragma unroll
        for (int j = 0; j < 9; ++j) h1[j] = fmaf(xi, fxW1[(16 + i) * 9 + j], h1[j]);
    }
    #pragma unroll
    for (int j = 0; j < 9; ++j) h1[j] = fmaxf(h1[j], 0.f);

    float h2[9];
    #pragma unroll
    for (int j = 0; j < 9; ++j) h2[j] = fxb2[j];
    #pragma unroll
    for (int i = 0; i < 9; ++i) {
        const float xi = h1[i];
        #pragma unroll
        for (int j = 0; j < 9; ++j) h2[j] = fmaf(xi, fxW2[i * 9 + j], h2[j]);
    }
    #pragma unroll
    for (int j = 0; j < 9; ++j) h2[j] = fmaxf(h2[j], 0.f);

    float o[16];
    #pragma unroll
    for (int k = 0; k < 16; ++k) o[k] = fxb3[k];
    #pragma unroll
    for (int j = 0; j < 9; ++j) {
        const float hj = h2[j];
        #pragma unroll
        for (int k = 0; k < 16; ++k) o[k] = fmaf(hj, fxW3[j * 16 + k], o[k]);
    }

    float4* po = reinterpret_cast<float4*>(Xout + (size_t)n * 16);
    #pragma unroll
    for (int q = 0; q < 4; ++q) {
        float4 v;
        v.x = o[4*q]; v.y = o[4*q+1]; v.z = o[4*q+2]; v.w = o[4*q+3];
        po[q] = v;
    }

    // base1 / base_s for NEXT round's edge kernel
    float bb[9];
    #pragma unroll
    for (int j = 0; j < 9; ++j) bb[j] = feb1[j];
    #pragma unroll
    for (int i = 0; i < 16; ++i) {
        const float xi = o[i];
        #pragma unroll
        for (int j = 0; j < 9; ++j) bb[j] = fmaf(xi, feW1[i * 9 + j], bb[j]);
    }
    float* bp = base1out + (size_t)n * 12;
    #pragma unroll
    for (int j = 0; j < 9; ++j) bp[j] = bb[j];

    float cc[9];
    #pragma unroll
    for (int j = 0; j < 9; ++j) cc[j] = 0.f;
    #pragma unroll
    for (int i = 0; i < 16; ++i) {
        const float xi = o[i];
        #pragma unroll
        for (int j = 0; j < 9; ++j) cc[j] = fmaf(xi, feW1[(16 + i) * 9 + j], cc[j]);
    }
    uint4 pv;
    pv.x = packh2(cc[0], cc[1]);
    pv.y = packh2(cc[2], cc[3]);
    pv.z = packh2(cc[4], cc[5]);
    pv.w = packh2(cc[6], cc[7]);
    *reinterpret_cast<uint4*>(basesh + (size_t)n * 16) = pv;
    *reinterpret_cast<unsigned*>(basesh + (size_t)n * 16 + 8) = packh2(cc[8], 0.f);
}

extern "C" void kernel_launch(void* const* d_in, const int* in_sizes, int n_in,
                              void* d_out, int out_size, void* d_ws, size_t ws_size,
                              hipStream_t stream)
{
    (void)in_sizes; (void)n_in; (void)out_size; (void)ws_size;
    const float* X0   = (const float*)d_in[0];
    const int*   esrc = (const int*)d_in[1];
    const int*   edst = (const int*)d_in[2];
    const float* feW1 = (const float*)d_in[3];
    const float* feb1 = (const float*)d_in[4];
    const float* feW2 = (const float*)d_in[5];
    const float* feb2 = (const float*)d_in[6];
    const float* feW3 = (const float*)d_in[7];
    const float* feb3 = (const float*)d_in[8];
    const float* fxW1 = (const float*)d_in[9];
    const float* fxb1 = (const float*)d_in[10];
    const float* fxW2 = (const float*)d_in[11];
    const float* fxb2 = (const float*)d_in[12];
    const float* fxW3 = (const float*)d_in[13];
    const float* fxb3 = (const float*)d_in[14];
    float* out = (float*)d_out;

    // workspace layout. all offsets 64B-aligned:
    //   base1: NN*12 f32 = 4,800,000 B; basesh: NN*16 half = 3,200,000 B;
    //   mb: NN*10 f32 = 4,000,000 B.
    float* base1   = (float*)d_ws;                        // NN*12 f32
    __half* basesh = (__half*)(base1 + (size_t)NN * 12);  // NN*16 half (32B rows)
    float* mb      = (float*)(basesh + (size_t)NN * 16);  // NN*10 f32
    int* gcursor   = (int*)(mb + (size_t)NN * 10);        // NBK (padded to 1024)
    unsigned* sed  = (unsigned*)(gcursor + 1024);         // NBK*SLOT u32 = 25.6MB

    const dim3 thr(256);
    const dim3 gS(NBLK_SORT);          // 782
    const dim3 gL(NBK);                // 782
    const dim3 gE(NBK * (SLOT / 256)); // 25024
    const dim3 gN(NB_NODE);            // 391

    // ---- two-level sort (once per launch) ----
    hipMemsetAsync(gcursor, 0, NBK * sizeof(int), stream);
    bsort_k<<<gS, thr, 0, stream>>>(esrc, edst, gcursor, sed);
    lsort_k<<<gL, dim3(512), 0, stream>>>(sed, gcursor);

    // ---- round 0 ----
    base_k<<<gN, thr, 0, stream>>>(X0, feW1, feb1, base1, basesh, mb);
    edge13_k<<<gE, thr, 0, stream>>>(base1, basesh, sed, gcursor, feW2, feb2, mb);
    node11_k<<<gN, thr, 0, stream>>>(X0, mb, fxW1, fxb1, fxW2, fxb2, fxW3, fxb3,
                                     feW1, feb1, feW3, feb3, out, base1, basesh);
    // ---- round 1 (node updates out in place; edge never reads X) ----
    edge13_k<<<gE, thr, 0, stream>>>(base1, basesh, sed, gcursor, feW2, feb2, mb);
    node11_k<<<gN, thr, 0, stream>>>(out, mb, fxW1, fxb1, fxW2, fxb2, fxW3, fxb3,
                                     feW1, feb1, feW3, feb3, out, base1, basesh);
    // ---- round 2 ----
    edge13_k<<<gE, thr, 0, stream>>>(base1, basesh, sed, gcursor, feW2, feb2, mb);
    node11_k<<<gN, thr, 0, stream>>>(out, mb, fxW1, fxb1, fxW2, fxb2, fxW3, fxb3,
                                     feW1, feb1, feW3, feb3, out, base1, basesh);
}